// Round 6
// baseline (656.071 us; speedup 1.0000x reference)
//
#include <hip/hip_runtime.h>
#include <stdint.h>

typedef short v8s __attribute__((ext_vector_type(8)));
typedef float v4f __attribute__((ext_vector_type(4)));

__device__ __forceinline__ float bf2f(short s) {
    unsigned int u = ((unsigned int)(unsigned short)s) << 16;
    float f; __builtin_memcpy(&f, &u, 4); return f;
}
__device__ __forceinline__ unsigned short f2bf_rne(float f) {
    unsigned int u; __builtin_memcpy(&u, &f, 4);
    return (unsigned short)((u + 0x7FFFu + ((u >> 16) & 1u)) >> 16);
}
__device__ __forceinline__ unsigned short f2bf_rhu(float f) {  // round-half-up (2 ops)
    unsigned int u; __builtin_memcpy(&u, &f, 4);
    return (unsigned short)((u + 0x8000u) >> 16);
}
__device__ __forceinline__ unsigned short f2bf_trunc(float f) {  // 1 op
    unsigned int u; __builtin_memcpy(&u, &f, 4);
    return (unsigned short)(u >> 16);
}
__device__ __forceinline__ float tanh_fast(float z) {
    float e = __expf(2.0f * z);
    float r = __builtin_amdgcn_rcpf(e + 1.0f);
    return __builtin_fmaf(-2.0f, r, 1.0f);
}

// ---------------------------------------------------------------------------
// Phase A: ux[t][b][i] = sum_e x[b][t][e]*Uw[i][e] + Ub[i] + Wb[i]   (f32)
// Block 0 additionally zeroes the sync area (ticket + per-tile flags).
// ---------------------------------------------------------------------------
__global__ __launch_bounds__(256) void ux_kernel(
    const float* __restrict__ x, const float* __restrict__ Uw,
    const float* __restrict__ Ub, const float* __restrict__ Wb,
    float* __restrict__ ux, unsigned* __restrict__ sync) {
    if (blockIdx.x == 0) {
        for (int i = threadIdx.x; i < 864; i += 256) sync[i] = 0;
    }
    int row = blockIdx.x * 2 + (threadIdx.x >> 7);  // row = t*32 + b
    int i = threadIdx.x & 127;
    int b = row & 31, t = row >> 5;
    const float* xr = x + (b * 200 + t) * 32;
    const float* ur = Uw + i * 32;
    float acc = 0.f;
#pragma unroll
    for (int e4 = 0; e4 < 8; ++e4) {
        v4f xv = *(const v4f*)(xr + e4 * 4);
        v4f uv = *(const v4f*)(ur + e4 * 4);
#pragma unroll
        for (int j = 0; j < 4; ++j) acc = __builtin_fmaf(xv[j], uv[j], acc);
    }
    ux[row * 128 + i] = acc + Ub[i] + Wb[i];
}

// ---------------------------------------------------------------------------
// Fused producer-consumer kernel, grid = 256 x 512.
//
// THIS ROUND'S single change: hbuf is DYNAMIC LDS and the launch requests
// 96 KiB/block -> the hardware can place only ONE block per CU (160 KiB LDS
// pool). Rounds 1-5 all allowed 4+ blocks/CU (17.9 KiB), so consumer blocks
// could co-reside on the producer CUs: 2 producer waves vs up to 6 consumer
// waves per SIMD in round-robin issue = the invariant ~2x producer slowdown
// (standalone round-0 rnn with grid=2 had no cohabitants and was fast).
// With 256 blocks / 256 CUs / 1 block per CU, producers own their CUs.
//
// Coherence protocol (unchanged from rounds 4/5 -- no cache maintenance):
//   * producer hs stores: relaxed AGENT atomics (sc1 -> LLC-direct),
//   * flag release: RELAXED agent fetch_add, preceded by a full
//     __syncthreads() (vmcnt(0) in every wave -> all tile stores LLC-acked),
//   * consumers: relaxed agent spin, then ordinary hs loads (lines never
//     cached locally; LLC copy is fresh).
// Producer schedule (unchanged from round 5): lgkm-only barriers on steps
// 1-3 of each 4-step group, full __syncthreads on step 4; 2-deep ux prefetch.
// ---------------------------------------------------------------------------
#define RAWBAR asm volatile("s_waitcnt lgkmcnt(0)\n\ts_barrier" ::: "memory")

__global__ __launch_bounds__(512) void fused_kernel(
    const float* __restrict__ Ww, const float* __restrict__ ux,
    short* __restrict__ hs, float* __restrict__ hidden_out,
    const float* __restrict__ Vw, const float* __restrict__ Vb,
    float* __restrict__ out, unsigned* __restrict__ sync) {
    // dynamic LDS; launch passes 98304 B so only one block fits per CU.
    // producer uses the first 2*2*16*136 shorts = 34816 B:
    // [buf][hi=0/lo=1][row 16][col 136]; strides: buf 8704B, plane 4352B, row 272B
    extern __shared__ short hbuf[];
    __shared__ unsigned s_ticket;
    const int tid = threadIdx.x;

    if (tid == 0)
        s_ticket = __hip_atomic_fetch_add(sync, 1u, __ATOMIC_RELAXED,
                                          __HIP_MEMORY_SCOPE_AGENT);
    __syncthreads();
    const unsigned ticket = s_ticket;

    const int w = tid >> 6, lane = tid & 63, q = lane >> 4, c = lane & 15;

    if (ticket < 2) {
        // ------------------------------ producer ------------------------------
        char* lds = (char*)hbuf;
        const int b0 = (int)ticket * 16;
        const int col = 16 * w + c;

        // zero both buffers (h0 = 0), 16B stores
        for (int i = tid; i < 1088; i += 512)
            ((v8s*)hbuf)[i] = (v8s){0, 0, 0, 0, 0, 0, 0, 0};

        // Ww B-fragments, split hi/lo: B[k][n]=Ww[n][k]; lane: n=col, k=32kb+8q+j
        v8s w_hi[4], w_lo[4];
#pragma unroll
        for (int kb = 0; kb < 4; ++kb) {
            const float* p = Ww + col * 128 + 32 * kb + 8 * q;
#pragma unroll
            for (int j = 0; j < 8; ++j) {
                float v = p[j];
                unsigned short hi = f2bf_rne(v);
                w_hi[kb][j] = (short)hi;
                w_lo[kb][j] = (short)f2bf_rne(v - bf2f((short)hi));
            }
        }

        const int rd_base = c * 272 + 16 * q;   // A-frag: row c, k-offset 8q (bytes)
        const int wr_base = q * 1088 + col * 2; // C rows 4q+r, col (bytes)

        // 2-deep ux prefetch: uxA = even-step values, uxB = odd-step values.
        // Load t=0 and t=1 now; uxp then points at t=2. Each step consumes its
        // slot and immediately re-issues loads 2 steps ahead into the SAME
        // slot (consume-before-reissue => no copy between load and use).
        const float* uxp = ux + (b0 + 4 * q) * 128 + col;
        v4f uxA = {uxp[0], uxp[128], uxp[256], uxp[384]};
        v4f uxB = {uxp[4096], uxp[4224], uxp[4352], uxp[4480]};
        uxp += 8192;
        short* hsp = hs + (b0 + 4 * q) * 128 + col;  // [t][b][h], t-stride 4096

        __syncthreads();

#define RNN_STEP(RBUF, WBUF, UXS, SYNC)                                             \
    {                                                                               \
        v4f a0 = UXS;  /* consume loads issued 2 steps ago */                       \
        UXS[0] = uxp[0]; UXS[1] = uxp[128]; UXS[2] = uxp[256]; UXS[3] = uxp[384];   \
        v4f a1 = {0.f, 0.f, 0.f, 0.f}, a2 = a1;                                     \
        _Pragma("unroll") for (int kb = 0; kb < 4; ++kb) {                          \
            v8s ahi = *(const v8s*)(lds + (RBUF)*8704 + kb * 64 + rd_base);         \
            v8s alo = *(const v8s*)(lds + (RBUF)*8704 + 4352 + kb * 64 + rd_base);  \
            a0 = __builtin_amdgcn_mfma_f32_16x16x32_bf16(ahi, w_hi[kb], a0, 0, 0, 0); \
            a1 = __builtin_amdgcn_mfma_f32_16x16x32_bf16(ahi, w_lo[kb], a1, 0, 0, 0); \
            a2 = __builtin_amdgcn_mfma_f32_16x16x32_bf16(alo, w_hi[kb], a2, 0, 0, 0); \
        }                                                                           \
        _Pragma("unroll") for (int r = 0; r < 4; ++r) {                             \
            float z = (a0[r] + a1[r]) + a2[r];                                      \
            float h = tanh_fast(z);                                                 \
            unsigned short hh = f2bf_rhu(h);                                        \
            float rem = h - bf2f((short)hh);                                        \
            unsigned short hl = f2bf_trunc(rem);                                    \
            *(short*)(lds + (WBUF)*8704 + r * 272 + wr_base) = (short)hh;           \
            *(short*)(lds + (WBUF)*8704 + 4352 + r * 272 + wr_base) = (short)hl;    \
            __hip_atomic_store(hsp + r * 128, (short)hh, __ATOMIC_RELAXED,          \
                               __HIP_MEMORY_SCOPE_AGENT);                           \
        }                                                                           \
        uxp += 4096; hsp += 4096;                                                   \
        SYNC;                                                                       \
    }

        for (int it = 0; it < 50; ++it) {
            // 4 steps = one tb-tile of 128 hs rows. Steps 1-3: lgkm-only
            // barrier (LDS deps only; sc1 store-acks drain in background).
            // Step 4: full __syncthreads() -> every wave at vmcnt(0) -> all
            // tile stores LLC-acked -> tid0's RELAXED agent add publishes.
            RNN_STEP(0, 1, uxA, RAWBAR)
            RNN_STEP(1, 0, uxB, RAWBAR)
            RNN_STEP(0, 1, uxA, RAWBAR)
            RNN_STEP(1, 0, uxB, __syncthreads())
            // note: prefetch reads up to 32KB past ux at the end (into the hs
            // region of d_ws) — in-bounds of ws, values never used.
            if (tid == 0)
                __hip_atomic_fetch_add(sync + 16 + it * 16, 1u,
                                       __ATOMIC_RELAXED, __HIP_MEMORY_SCOPE_AGENT);
        }
#undef RNN_STEP

        // final h (t=199 wrote buf0); each lane reads its own writes — no barrier
#pragma unroll
        for (int r = 0; r < 4; ++r) {
            short hh = *(short*)(lds + r * 272 + wr_base);
            short hl = *(short*)(lds + 4352 + r * 272 + wr_base);
            hidden_out[(b0 + 4 * q + r) * 128 + col] = bf2f(hh) + bf2f(hl);
        }
        return;
    }

    // ------------------------------ consumer ------------------------------
    const int cid0 = (int)ticket - 2;           // 0..253
    const int v_tile = cid0 & 31;               // FIXED for this block
    const int g = cid0 >> 5;                    // tb residue class 0..7
    const int v_wave = v_tile * 256 + 32 * w;

    // Hoisted: Vw bf16 A-fragments (RNE, identical numerics to old vwcvt) + Vb
    v8s afr[4][2];
#pragma unroll
    for (int kb = 0; kb < 4; ++kb)
#pragma unroll
        for (int vt = 0; vt < 2; ++vt) {
            int vr = v_wave + 16 * vt + c;
            vr = vr < 8000 ? vr : 7999;  // OOB rows: garbage acc, store-masked
            const float* ap = Vw + vr * 128 + 32 * kb + 8 * q;
            v4f p0 = *(const v4f*)ap;
            v4f p1 = *(const v4f*)(ap + 4);
#pragma unroll
            for (int j = 0; j < 4; ++j) {
                afr[kb][vt][j] = (short)f2bf_rne(p0[j]);
                afr[kb][vt][4 + j] = (short)f2bf_rne(p1[j]);
            }
        }
    v4f vbv[2];
    bool okv[2];
    int v4b[2];
#pragma unroll
    for (int vt = 0; vt < 2; ++vt) {
        v4b[vt] = v_wave + 16 * vt + 4 * q;     // lane's 4 consecutive v
        okv[vt] = v4b[vt] < 8000;               // tile-aligned, 8000 % 4 == 0
        vbv[vt] = *(const v4f*)(Vb + (okv[vt] ? v4b[vt] : 0));
    }

    auto do_tile = [&](int tb) {
        const int n0 = tb * 128;

        unsigned* flag = sync + 16 + tb * 16;
        if (tid == 0) {
            // relaxed agent load (LLC-served, always fresh); s_sleep backoff.
            // No ACQUIRE needed: hs lines were never cached in this block's
            // L1/L2, and producer sc1 stores are LLC-acked before the flag.
            while (__hip_atomic_load(flag, __ATOMIC_RELAXED,
                                     __HIP_MEMORY_SCOPE_AGENT) < 2u)
                __builtin_amdgcn_s_sleep(32);
        }
        __syncthreads();

        v4f acc[2][8];
#pragma unroll
        for (int a = 0; a < 2; ++a)
#pragma unroll
            for (int b = 0; b < 8; ++b) acc[a][b] = (v4f){0.f, 0.f, 0.f, 0.f};

#pragma unroll
        for (int kb = 0; kb < 4; ++kb) {
#pragma unroll
            for (int nt = 0; nt < 8; ++nt) {
                v8s bfr = *(const v8s*)(hs + (n0 + 16 * nt + c) * 128 + 32 * kb + 8 * q);
                acc[0][nt] = __builtin_amdgcn_mfma_f32_16x16x32_bf16(afr[kb][0], bfr, acc[0][nt], 0, 0, 0);
                acc[1][nt] = __builtin_amdgcn_mfma_f32_16x16x32_bf16(afr[kb][1], bfr, acc[1][nt], 0, 0, 0);
            }
        }

#pragma unroll
        for (int vt = 0; vt < 2; ++vt) {
#pragma unroll
            for (int nt = 0; nt < 8; ++nt) {
                int n = n0 + 16 * nt + c;       // tb index
                int t = n >> 5, b = n & 31;
                unsigned int off = (unsigned int)(b * 200 + t) * 8000u + (unsigned int)v4b[vt];
                if (okv[vt]) {
                    v4f o;
#pragma unroll
                    for (int r = 0; r < 4; ++r) o[r] = acc[vt][nt][r] + vbv[vt][r];
                    *(v4f*)(out + (size_t)off) = o;
                }
            }
        }
    };

    for (int tb = g; tb < 50; tb += 8) do_tile(tb);   // ascending -> flag order
    // Patch chain: tiles (tb === 7 mod 8, v in {30,31}) have no cid0 = 224+v
    // owner (grid is 256 = 2 producers + 254 consumers). Blocks 30/31 (g=0,
    // same v) pick them up after their own chain.
    if (cid0 == 30 || cid0 == 31)
        for (int tb = 7; tb < 50; tb += 8) do_tile(tb);
}

extern "C" void kernel_launch(void* const* d_in, const int* in_sizes, int n_in,
                              void* d_out, int out_size, void* d_ws, size_t ws_size,
                              hipStream_t stream) {
    const float* x  = (const float*)d_in[0];  // [32][200][32]
    const float* Ww = (const float*)d_in[1];  // [128][128]
    const float* Wb = (const float*)d_in[2];  // [128]
    const float* Uw = (const float*)d_in[3];  // [128][32]
    const float* Ub = (const float*)d_in[4];  // [128]
    const float* Vw = (const float*)d_in[5];  // [8000][128]
    const float* Vb = (const float*)d_in[6];  // [8000]
    float* out = (float*)d_out;               // [32][200][8000] ++ [32][128]

    float* ux = (float*)d_ws;                          // 819200 f32 = 3.277 MB
    short* hs = (short*)((char*)d_ws + 3276800);       // 819200 bf16 = 1.638 MB
    unsigned* sync = (unsigned*)((char*)d_ws + 4915200); // ticket + 50 flags

    ux_kernel<<<3200, 256, 0, stream>>>(x, Uw, Ub, Wb, ux, sync);
    // 96 KiB dynamic LDS -> exactly one block per CU (160 KiB pool).
    fused_kernel<<<256, 512, 98304, stream>>>(Ww, ux, hs, out + 51200000,
                                              Vw, Vb, out, sync);
}

// Round 7
// 403.789 us; speedup vs baseline: 1.6248x; 1.6248x over previous
//
#include <hip/hip_runtime.h>
#include <stdint.h>

typedef short v8s __attribute__((ext_vector_type(8)));
typedef float v4f __attribute__((ext_vector_type(4)));

__device__ __forceinline__ float bf2f(short s) {
    unsigned int u = ((unsigned int)(unsigned short)s) << 16;
    float f; __builtin_memcpy(&f, &u, 4); return f;
}
__device__ __forceinline__ unsigned short f2bf_rne(float f) {
    unsigned int u; __builtin_memcpy(&u, &f, 4);
    return (unsigned short)((u + 0x7FFFu + ((u >> 16) & 1u)) >> 16);
}
__device__ __forceinline__ unsigned short f2bf_rhu(float f) {  // round-half-up (2 ops)
    unsigned int u; __builtin_memcpy(&u, &f, 4);
    return (unsigned short)((u + 0x8000u) >> 16);
}
__device__ __forceinline__ unsigned short f2bf_trunc(float f) {  // 1 op
    unsigned int u; __builtin_memcpy(&u, &f, 4);
    return (unsigned short)(u >> 16);
}
__device__ __forceinline__ float tanh_fast(float z) {
    float e = __expf(2.0f * z);
    float r = __builtin_amdgcn_rcpf(e + 1.0f);
    return __builtin_fmaf(-2.0f, r, 1.0f);
}

// ---------------------------------------------------------------------------
// Phase A: ux[t][b][i] = sum_e x[b][t][e]*Uw[i][e] + Ub[i] + Wb[i]   (f32)
// Block 0 additionally zeroes the sync area (ticket + per-tile flags).
// ---------------------------------------------------------------------------
__global__ __launch_bounds__(256) void ux_kernel(
    const float* __restrict__ x, const float* __restrict__ Uw,
    const float* __restrict__ Ub, const float* __restrict__ Wb,
    float* __restrict__ ux, unsigned* __restrict__ sync) {
    if (blockIdx.x == 0) {
        for (int i = threadIdx.x; i < 864; i += 256) sync[i] = 0;
    }
    int row = blockIdx.x * 2 + (threadIdx.x >> 7);  // row = t*32 + b
    int i = threadIdx.x & 127;
    int b = row & 31, t = row >> 5;
    const float* xr = x + (b * 200 + t) * 32;
    const float* ur = Uw + i * 32;
    float acc = 0.f;
#pragma unroll
    for (int e4 = 0; e4 < 8; ++e4) {
        v4f xv = *(const v4f*)(xr + e4 * 4);
        v4f uv = *(const v4f*)(ur + e4 * 4);
#pragma unroll
        for (int j = 0; j < 4; ++j) acc = __builtin_fmaf(xv[j], uv[j], acc);
    }
    ux[row * 128 + i] = acc + Ub[i] + Wb[i];
}

// ---------------------------------------------------------------------------
// Fused producer-consumer kernel, grid = 256 x 512, static LDS (~17.9 KB ->
// multi-block/CU packing allowed; round 6 proved 1-block/CU starves the
// consumers, which are the actual bound).
//
// ROUND-7 DIAGNOSIS: fused duration is CONSUMER-store-bandwidth limited.
// The old epilogue stored 16 scattered 64B segments per wave-store
// (c = lane&15 selects one of 16 different 32KB output rows) -> ~1.3 TB/s.
// NEW: stage each 16-row result chunk in LDS ([16][260] f32, +4 pad -> only
// free 2-way conflicts), then each wave stores ONE output row segment:
// 64 lanes x 16B = 1KB fully contiguous per store instruction. Chunk
// barriers are lgkmcnt-only, so global stores pipeline freely across chunks.
//
// Coherence protocol (unchanged, no cache maintenance): producer hs stores
// relaxed AGENT sc1 (LLC-direct); full __syncthreads (vmcnt(0) drain) then
// RELAXED agent flag add every 4 steps; consumers relaxed-spin then ordinary
// hs loads (never locally cached -> LLC copy is fresh).
// Producer schedule (unchanged from round 5): lgkm-only barriers steps 1-3,
// __syncthreads on step 4; 2-deep ux prefetch.
// ---------------------------------------------------------------------------
#define RAWBAR asm volatile("s_waitcnt lgkmcnt(0)\n\ts_barrier" ::: "memory")

__global__ __launch_bounds__(512) void fused_kernel(
    const float* __restrict__ Ww, const float* __restrict__ ux,
    short* __restrict__ hs, float* __restrict__ hidden_out,
    const float* __restrict__ Vw, const float* __restrict__ Vb,
    float* __restrict__ out, unsigned* __restrict__ sync) {
    // producer: [buf][hi/lo][row 16][col 136] shorts (34816B... = 17408B x2)
    // consumer: reuses the same LDS as [16][260] f32 staging (16640 B)
    __shared__ alignas(16) short hbuf[2 * 2 * 16 * 136];
    __shared__ unsigned s_ticket;
    const int tid = threadIdx.x;

    if (tid == 0)
        s_ticket = __hip_atomic_fetch_add(sync, 1u, __ATOMIC_RELAXED,
                                          __HIP_MEMORY_SCOPE_AGENT);
    __syncthreads();
    const unsigned ticket = s_ticket;

    const int w = tid >> 6, lane = tid & 63, q = lane >> 4, c = lane & 15;

    if (ticket < 2) {
        // ------------------------------ producer ------------------------------
        char* lds = (char*)hbuf;
        const int b0 = (int)ticket * 16;
        const int col = 16 * w + c;

        // zero both buffers (h0 = 0), 16B stores
        for (int i = tid; i < 1088; i += 512)
            ((v8s*)hbuf)[i] = (v8s){0, 0, 0, 0, 0, 0, 0, 0};

        // Ww B-fragments, split hi/lo: B[k][n]=Ww[n][k]; lane: n=col, k=32kb+8q+j
        v8s w_hi[4], w_lo[4];
#pragma unroll
        for (int kb = 0; kb < 4; ++kb) {
            const float* p = Ww + col * 128 + 32 * kb + 8 * q;
#pragma unroll
            for (int j = 0; j < 8; ++j) {
                float v = p[j];
                unsigned short hi = f2bf_rne(v);
                w_hi[kb][j] = (short)hi;
                w_lo[kb][j] = (short)f2bf_rne(v - bf2f((short)hi));
            }
        }

        const int rd_base = c * 272 + 16 * q;   // A-frag: row c, k-offset 8q (bytes)
        const int wr_base = q * 1088 + col * 2; // C rows 4q+r, col (bytes)

        // 2-deep ux prefetch (uxA even steps, uxB odd steps)
        const float* uxp = ux + (b0 + 4 * q) * 128 + col;
        v4f uxA = {uxp[0], uxp[128], uxp[256], uxp[384]};
        v4f uxB = {uxp[4096], uxp[4224], uxp[4352], uxp[4480]};
        uxp += 8192;
        short* hsp = hs + (b0 + 4 * q) * 128 + col;  // [t][b][h], t-stride 4096

        __syncthreads();

#define RNN_STEP(RBUF, WBUF, UXS, SYNC)                                             \
    {                                                                               \
        v4f a0 = UXS;  /* consume loads issued 2 steps ago */                       \
        UXS[0] = uxp[0]; UXS[1] = uxp[128]; UXS[2] = uxp[256]; UXS[3] = uxp[384];   \
        v4f a1 = {0.f, 0.f, 0.f, 0.f}, a2 = a1;                                     \
        _Pragma("unroll") for (int kb = 0; kb < 4; ++kb) {                          \
            v8s ahi = *(const v8s*)(lds + (RBUF)*8704 + kb * 64 + rd_base);         \
            v8s alo = *(const v8s*)(lds + (RBUF)*8704 + 4352 + kb * 64 + rd_base);  \
            a0 = __builtin_amdgcn_mfma_f32_16x16x32_bf16(ahi, w_hi[kb], a0, 0, 0, 0); \
            a1 = __builtin_amdgcn_mfma_f32_16x16x32_bf16(ahi, w_lo[kb], a1, 0, 0, 0); \
            a2 = __builtin_amdgcn_mfma_f32_16x16x32_bf16(alo, w_hi[kb], a2, 0, 0, 0); \
        }                                                                           \
        _Pragma("unroll") for (int r = 0; r < 4; ++r) {                             \
            float z = (a0[r] + a1[r]) + a2[r];                                      \
            float h = tanh_fast(z);                                                 \
            unsigned short hh = f2bf_rhu(h);                                        \
            float rem = h - bf2f((short)hh);                                        \
            unsigned short hl = f2bf_trunc(rem);                                    \
            *(short*)(lds + (WBUF)*8704 + r * 272 + wr_base) = (short)hh;           \
            *(short*)(lds + (WBUF)*8704 + 4352 + r * 272 + wr_base) = (short)hl;    \
            __hip_atomic_store(hsp + r * 128, (short)hh, __ATOMIC_RELAXED,          \
                               __HIP_MEMORY_SCOPE_AGENT);                           \
        }                                                                           \
        uxp += 4096; hsp += 4096;                                                   \
        SYNC;                                                                       \
    }

        for (int it = 0; it < 50; ++it) {
            RNN_STEP(0, 1, uxA, RAWBAR)
            RNN_STEP(1, 0, uxB, RAWBAR)
            RNN_STEP(0, 1, uxA, RAWBAR)
            RNN_STEP(1, 0, uxB, __syncthreads())
            // note: prefetch reads up to 32KB past ux at the end (into the hs
            // region of d_ws) — in-bounds of ws, values never used.
            if (tid == 0)
                __hip_atomic_fetch_add(sync + 16 + it * 16, 1u,
                                       __ATOMIC_RELAXED, __HIP_MEMORY_SCOPE_AGENT);
        }
#undef RNN_STEP

        // final h (t=199 wrote buf0); each lane reads its own writes — no barrier
#pragma unroll
        for (int r = 0; r < 4; ++r) {
            short hh = *(short*)(lds + r * 272 + wr_base);
            short hl = *(short*)(lds + 4352 + r * 272 + wr_base);
            hidden_out[(b0 + 4 * q + r) * 128 + col] = bf2f(hh) + bf2f(hl);
        }
        return;
    }

    // ------------------------------ consumer ------------------------------
    const int cid0 = (int)ticket - 2;           // 0..253
    const int v_tile = cid0 & 31;               // FIXED for this block
    const int g = cid0 >> 5;                    // tb residue class 0..7
    const int v_wave = v_tile * 256 + 32 * w;
    float* ldsF = (float*)hbuf;                 // [16][260] staging

    // Hoisted: Vw bf16 A-fragments (RNE, identical numerics to old vwcvt) + Vb
    v8s afr[4][2];
#pragma unroll
    for (int kb = 0; kb < 4; ++kb)
#pragma unroll
        for (int vt = 0; vt < 2; ++vt) {
            int vr = v_wave + 16 * vt + c;
            vr = vr < 8000 ? vr : 7999;  // OOB rows: garbage acc, store-masked
            const float* ap = Vw + vr * 128 + 32 * kb + 8 * q;
            v4f p0 = *(const v4f*)ap;
            v4f p1 = *(const v4f*)(ap + 4);
#pragma unroll
            for (int j = 0; j < 4; ++j) {
                afr[kb][vt][j] = (short)f2bf_rne(p0[j]);
                afr[kb][vt][4 + j] = (short)f2bf_rne(p1[j]);
            }
        }
    v4f vbv[2];
#pragma unroll
    for (int vt = 0; vt < 2; ++vt) {
        int v4b = v_wave + 16 * vt + 4 * q;     // lane's 4 acc v-positions
        vbv[vt] = *(const v4f*)(Vb + (v4b < 8000 ? v4b : 0));
    }
    // coalesced-store column for this lane: 4 consecutive v within the 256-v tile
    const int vcol = v_tile * 256 + 4 * lane;
    const bool vok = vcol < 8000;               // tile-aligned (8000 % 4 == 0)

    auto do_tile = [&](int tb) {
        const int n0 = tb * 128;

        unsigned* flag = sync + 16 + tb * 16;
        if (tid == 0) {
            while (__hip_atomic_load(flag, __ATOMIC_RELAXED,
                                     __HIP_MEMORY_SCOPE_AGENT) < 2u)
                __builtin_amdgcn_s_sleep(32);
        }
        __syncthreads();

        v4f acc[2][8];
#pragma unroll
        for (int a = 0; a < 2; ++a)
#pragma unroll
            for (int b = 0; b < 8; ++b) acc[a][b] = (v4f){0.f, 0.f, 0.f, 0.f};

#pragma unroll
        for (int kb = 0; kb < 4; ++kb) {
#pragma unroll
            for (int nt = 0; nt < 8; ++nt) {
                v8s bfr = *(const v8s*)(hs + (n0 + 16 * nt + c) * 128 + 32 * kb + 8 * q);
                acc[0][nt] = __builtin_amdgcn_mfma_f32_16x16x32_bf16(afr[kb][0], bfr, acc[0][nt], 0, 0, 0);
                acc[1][nt] = __builtin_amdgcn_mfma_f32_16x16x32_bf16(afr[kb][1], bfr, acc[1][nt], 0, 0, 0);
            }
        }

        // Epilogue: per 16-row chunk, stage in LDS then 1KB-contiguous stores.
#pragma unroll
        for (int nt = 0; nt < 8; ++nt) {
#pragma unroll
            for (int vt = 0; vt < 2; ++vt) {
                v4f o;
#pragma unroll
                for (int r = 0; r < 4; ++r) o[r] = acc[vt][nt][r] + vbv[vt][r];
                // row c, cols 32w+16vt+4q..+3; [16][260] pad -> 2-way (free)
                *(v4f*)&ldsF[c * 260 + 32 * w + 16 * vt + 4 * q] = o;
            }
            RAWBAR;  // LDS writes visible to all waves (no vmcnt drain)
#pragma unroll
            for (int half = 0; half < 2; ++half) {
                int row = w + 8 * half;         // wave-uniform row 0..15
                int n = n0 + 16 * nt + row;     // tb index
                int t = n >> 5, b = n & 31;
                v4f o = *(const v4f*)&ldsF[row * 260 + 4 * lane];
                if (vok)
                    *(v4f*)(out + (size_t)(b * 200 + t) * 8000 + vcol) = o;
            }
            RAWBAR;  // reads done before next chunk overwrites (stores fly on)
        }
    };

    for (int tb = g; tb < 50; tb += 8) do_tile(tb);   // ascending -> flag order
    // Patch chain: tiles (tb === 7 mod 8, v in {30,31}) have no cid0 = 224+v
    // owner (grid is 256 = 2 producers + 254 consumers). Blocks 30/31 (g=0,
    // same v) pick them up after their own chain.
    if (cid0 == 30 || cid0 == 31)
        for (int tb = 7; tb < 50; tb += 8) do_tile(tb);
}

extern "C" void kernel_launch(void* const* d_in, const int* in_sizes, int n_in,
                              void* d_out, int out_size, void* d_ws, size_t ws_size,
                              hipStream_t stream) {
    const float* x  = (const float*)d_in[0];  // [32][200][32]
    const float* Ww = (const float*)d_in[1];  // [128][128]
    const float* Wb = (const float*)d_in[2];  // [128]
    const float* Uw = (const float*)d_in[3];  // [128][32]
    const float* Ub = (const float*)d_in[4];  // [128]
    const float* Vw = (const float*)d_in[5];  // [8000][128]
    const float* Vb = (const float*)d_in[6];  // [8000]
    float* out = (float*)d_out;               // [32][200][8000] ++ [32][128]

    float* ux = (float*)d_ws;                          // 819200 f32 = 3.277 MB
    short* hs = (short*)((char*)d_ws + 3276800);       // 819200 bf16 = 1.638 MB
    unsigned* sync = (unsigned*)((char*)d_ws + 4915200); // ticket + 50 flags

    ux_kernel<<<3200, 256, 0, stream>>>(x, Uw, Ub, Wb, ux, sync);
    fused_kernel<<<256, 512, 0, stream>>>(Ww, ux, hs, out + 51200000,
                                          Vw, Vb, out, sync);
}